// Round 3
// baseline (1246.969 us; speedup 1.0000x reference)
//
#include <hip/hip_runtime.h>

typedef float f32x4 __attribute__((ext_vector_type(4)));
typedef __bf16 bf16x8 __attribute__((ext_vector_type(8)));
typedef unsigned short u16x8 __attribute__((ext_vector_type(8)));

#define DEVINL static __device__ __forceinline__

DEVINL unsigned short f2bf(float f) {
    unsigned int u = __builtin_bit_cast(unsigned int, f);
    u += 0x7fffu + ((u >> 16) & 1u);   // RNE
    return (unsigned short)(u >> 16);
}
DEVINL float bf2f(unsigned short u) {
    unsigned int x = ((unsigned int)u) << 16;
    return __builtin_bit_cast(float, x);
}

// async global->LDS, 16B per lane. LDS dest is wave-uniform base + lane*16;
// our chunk ids are consecutive within a wave so linear layout matches.
#define GLD16(gp, lp)                                                          \
    __builtin_amdgcn_global_load_lds(                                          \
        (const __attribute__((address_space(1))) void*)(gp),                   \
        (__attribute__((address_space(3))) void*)(lp), 16, 0, 0)

// ---------------- packing kernels ----------------
// concat two [rows,128] f32 sources into [rows,256] bf16
__global__ void pack_cat_k(const float* __restrict__ s0, const float* __restrict__ s1,
                           unsigned short* __restrict__ dst, int nchunks) {
    int e = blockIdx.x * 256 + threadIdx.x;   // one 8-elem chunk
    if (e >= nchunks) return;
    int row = e >> 5, ch = e & 31;
    const float* src = (ch < 16) ? (s0 + (size_t)row * 128 + ch * 8)
                                 : (s1 + (size_t)row * 128 + (ch - 16) * 8);
    float4 a = *(const float4*)src;
    float4 b = *(const float4*)(src + 4);
    u16x8 o;
    o[0] = f2bf(a.x); o[1] = f2bf(a.y); o[2] = f2bf(a.z); o[3] = f2bf(a.w);
    o[4] = f2bf(b.x); o[5] = f2bf(b.y); o[6] = f2bf(b.z); o[7] = f2bf(b.w);
    *(u16x8*)(dst + (size_t)e * 8) = o;
}

__global__ void cvt_k(const float* __restrict__ s, unsigned short* __restrict__ d, int nchunks) {
    int e = blockIdx.x * 256 + threadIdx.x;
    if (e >= nchunks) return;
    float4 a = *(const float4*)(s + (size_t)e * 8);
    float4 b = *(const float4*)(s + (size_t)e * 8 + 4);
    u16x8 o;
    o[0] = f2bf(a.x); o[1] = f2bf(a.y); o[2] = f2bf(a.z); o[3] = f2bf(a.w);
    o[4] = f2bf(b.x); o[5] = f2bf(b.y); o[6] = f2bf(b.z); o[7] = f2bf(b.w);
    *(u16x8*)(d + (size_t)e * 8) = o;
}

// ---------------- GEMM: C = epi(A @ B^T [+ bias]) ----------------
// A: [M,K] bf16 row-major, B: [N,K] bf16 row-major, C: [M,N] bf16.
// 128x128 tile, BK=32, 4 waves (2x2), each wave 64x64 via 4x4 16x16x32 MFMA.
// EPI: 0 = plain store, 1 = bias + swish
template <int EPI>
__global__ void gemm_bt_k(const unsigned short* __restrict__ A,
                          const unsigned short* __restrict__ B,
                          const float* __restrict__ bias,
                          unsigned short* __restrict__ C,
                          int M, int N, int K) {
    __shared__ unsigned short As[128 * 32];
    __shared__ unsigned short Bs[128 * 32];
    const int tid  = threadIdx.x;
    const int lane = tid & 63;
    const int wv   = tid >> 6;
    const int wr   = wv >> 1, wc = wv & 1;
    const int ntn  = N >> 7;
    const int im   = blockIdx.x / ntn, in = blockIdx.x % ntn;
    const size_t rowA0 = (size_t)im * 128, rowB0 = (size_t)in * 128;

    // staging chunk ids (16B each); 512 chunks per tile, 2 per thread per tile
    const int e0 = tid, e1 = tid + 256;
    const int ra0 = e0 >> 2, ca0 = (e0 & 3) * 8;
    const int ra1 = e1 >> 2, ca1 = (e1 & 3) * 8;

    f32x4 acc[4][4] = {};

    const int frow = lane & 15;          // fragment row within 16
    const int kb   = (lane >> 4) * 8;    // k-chunk base

    for (int k0 = 0; k0 < K; k0 += 32) {
        GLD16(A + (rowA0 + ra0) * K + k0 + ca0, (char*)As + e0 * 16);
        GLD16(A + (rowA0 + ra1) * K + k0 + ca1, (char*)As + e1 * 16);
        GLD16(B + (rowB0 + ra0) * K + k0 + ca0, (char*)Bs + e0 * 16);
        GLD16(B + (rowB0 + ra1) * K + k0 + ca1, (char*)Bs + e1 * 16);
        __syncthreads();   // drains vmcnt before barrier -> LDS valid

        bf16x8 af[4], bfr[4];
#pragma unroll
        for (int m = 0; m < 4; ++m)
            af[m] = *(const bf16x8*)&As[(wr * 64 + m * 16 + frow) * 32 + kb];
#pragma unroll
        for (int n = 0; n < 4; ++n)
            bfr[n] = *(const bf16x8*)&Bs[(wc * 64 + n * 16 + frow) * 32 + kb];
#pragma unroll
        for (int m = 0; m < 4; ++m)
#pragma unroll
            for (int n = 0; n < 4; ++n)
                acc[m][n] = __builtin_amdgcn_mfma_f32_16x16x32_bf16(af[m], bfr[n], acc[m][n], 0, 0, 0);
        __syncthreads();   // protect LDS before next stage
    }

    // epilogue: C/D layout col = lane&15, row = (lane>>4)*4 + reg
    const int r4 = (lane >> 4) * 4;
    const int cc = lane & 15;
#pragma unroll
    for (int n = 0; n < 4; ++n) {
        const int col = (int)rowB0 + wc * 64 + n * 16 + cc;
        const float bv = (EPI == 1) ? bias[col] : 0.0f;
#pragma unroll
        for (int m = 0; m < 4; ++m) {
            const size_t row = rowA0 + wr * 64 + m * 16 + r4;
#pragma unroll
            for (int r = 0; r < 4; ++r) {
                float v = acc[m][n][r] + bv;
                if (EPI == 1) v = v / (1.0f + __expf(-v));   // swish
                C[(row + r) * (size_t)N + col] = f2bf(v);
            }
        }
    }
}

// ---------------- node scores: sc[row] = h[row,:] . w_ns ----------------
__global__ void scores_k(const unsigned short* __restrict__ h,
                         const float* __restrict__ wns, float* __restrict__ sc) {
    const int lane = threadIdx.x & 63, wv = threadIdx.x >> 6;
    const size_t row = (size_t)blockIdx.x * 4 + wv;
    const unsigned short* p = h + row * 1024;
    float s = 0.f;
#pragma unroll
    for (int it = 0; it < 2; ++it) {
        const int base = (it * 64 + lane) * 8;
        u16x8 v = *(const u16x8*)&p[base];
        const float4 w0 = *(const float4*)&wns[base];
        const float4 w1 = *(const float4*)&wns[base + 4];
        s += bf2f(v[0]) * w0.x + bf2f(v[1]) * w0.y + bf2f(v[2]) * w0.z + bf2f(v[3]) * w0.w
           + bf2f(v[4]) * w1.x + bf2f(v[5]) * w1.y + bf2f(v[6]) * w1.z + bf2f(v[7]) * w1.w;
    }
#pragma unroll
    for (int off = 32; off; off >>= 1) s += __shfl_down(s, off);
    if (lane == 0) sc[row] = s;
}

// ---------------- segment mean pool (chunk-local): pool[b,h] += ... -------
// grid = (segs_in_chunk)*32; h is chunk base; pool already offset to chunk's
// first segment.
__global__ void pool_k(const unsigned short* __restrict__ h, float* __restrict__ pool) {
    const int bi = blockIdx.x;
    const int b = bi >> 5, sub = bi & 31;
    const int rb = sub >> 2, cb = sub & 3;           // 8 row-blocks x 4 col-blocks
    const int hc = cb * 256 + threadIdx.x;
    const unsigned short* p = h + ((size_t)b * 2048 + rb * 256) * 1024 + hc;
    float acc = 0.f;
#pragma unroll 8
    for (int r = 0; r < 256; ++r) acc += bf2f(p[(size_t)r * 1024]);
    atomicAdd(&pool[b * 1024 + hc], acc * (1.0f / 2048.0f));
}

// ---------------- stop head: log_softmax(pool @ W_stop^T) ----------------
__global__ void stop_k(const float* __restrict__ pool, const float* __restrict__ Wstop,
                       float* __restrict__ stp, float* __restrict__ out) {
    const int b = blockIdx.x, t = threadIdx.x;
    float a0 = 0.f, a1 = 0.f;
#pragma unroll
    for (int j = 0; j < 4; ++j) {
        const int hcol = t + j * 256;
        const float pv = pool[b * 1024 + hcol];
        a0 += pv * Wstop[hcol];
        a1 += pv * Wstop[1024 + hcol];
    }
    const int lane = t & 63, wv = t >> 6;
#pragma unroll
    for (int off = 32; off; off >>= 1) { a0 += __shfl_down(a0, off); a1 += __shfl_down(a1, off); }
    __shared__ float r0[4], r1[4];
    if (lane == 0) { r0[wv] = a0; r1[wv] = a1; }
    __syncthreads();
    if (t == 0) {
        const float s0 = r0[0] + r0[1] + r0[2] + r0[3];
        const float s1 = r1[0] + r1[1] + r1[2] + r1[3];
        const float m  = fmaxf(s0, s1);
        const float lse = m + __logf(__expf(s0 - m) + __expf(s1 - m));
        stp[b * 2] = s0 - lse;
        out[(size_t)b * 2049 + 2048] = s1 - lse;
    }
}

// ---------------- node logits: log_softmax over 2048 + stop0 ----------------
__global__ void node_k(const float* __restrict__ sc, const float* __restrict__ stp,
                       float* __restrict__ out) {
    const int b = blockIdx.x, t = threadIdx.x;
    const float* s = sc + (size_t)b * 2048;
    float v[8];
    float mx = -3.4e38f;
#pragma unroll
    for (int j = 0; j < 8; ++j) { v[j] = s[t + j * 256]; mx = fmaxf(mx, v[j]); }
    const int lane = t & 63, wv = t >> 6;
    __shared__ float red[4];
#pragma unroll
    for (int off = 32; off; off >>= 1) mx = fmaxf(mx, __shfl_down(mx, off));
    if (lane == 0) red[wv] = mx;
    __syncthreads();
    mx = fmaxf(fmaxf(red[0], red[1]), fmaxf(red[2], red[3]));
    float se = 0.f;
#pragma unroll
    for (int j = 0; j < 8; ++j) se += __expf(v[j] - mx);
    __syncthreads();
#pragma unroll
    for (int off = 32; off; off >>= 1) se += __shfl_down(se, off);
    if (lane == 0) red[wv] = se;
    __syncthreads();
    se = red[0] + red[1] + red[2] + red[3];
    const float base = stp[b * 2] - mx - __logf(se);
#pragma unroll
    for (int j = 0; j < 8; ++j) out[(size_t)b * 2049 + t + j * 256] = v[j] + base;
}

extern "C" void kernel_launch(void* const* d_in, const int* in_sizes, int n_in,
                              void* d_out, int out_size, void* d_ws, size_t ws_size,
                              hipStream_t stream) {
    (void)in_sizes; (void)n_in; (void)out_size;
    const float* x_seeds = (const float*)d_in[0];
    const float* x_nodes = (const float*)d_in[1];
    const float* W_seed  = (const float*)d_in[2];
    const float* W_node  = (const float*)d_in[3];
    const float* W1      = (const float*)d_in[4];
    const float* b1      = (const float*)d_in[5];
    const float* W2      = (const float*)d_in[6];
    const float* b2      = (const float*)d_in[7];
    const float* w_ns    = (const float*)d_in[8];
    const float* W_stop  = (const float*)d_in[9];
    float* out = (float*)d_out;

    const int N = 131072, H = 1024, B = 64;

    char* ws = (char*)d_ws;
    size_t off = 0;
    auto alloc = [&](size_t bytes) {
        char* p = ws + off;
        off += (bytes + 255) & ~(size_t)255;
        return p;
    };
    // ---- persistent (small) buffers ----
    unsigned short* wcat = (unsigned short*)alloc((size_t)H * 256 * 2);   // 0.5 MB
    unsigned short* W1b  = (unsigned short*)alloc((size_t)H * H * 2);     // 2 MB
    unsigned short* W2b  = (unsigned short*)alloc((size_t)H * H * 2);     // 2 MB
    float* scores = (float*)alloc((size_t)N * 4);                         // 0.5 MB
    float* pool   = (float*)alloc((size_t)B * H * 4);                     // 0.25 MB
    float* stp    = (float*)alloc((size_t)B * 2 * 4);

    // ---- chunk sizing from ws_size (row pipeline is chunkable by whole
    // 2048-row segments; per-row cost: 512B xcat + 2048B h0/h2 + 2048B h1) ----
    const size_t per_row = 256 * 2 + 1024 * 2 + 1024 * 2;   // 4608 B
    size_t avail = (ws_size > off + (1u << 20)) ? (ws_size - off - (1u << 20)) : 0;
    long long mc_ll = (long long)(avail / per_row) / 2048 * 2048;
    int Mc = (int)(mc_ll < 2048 ? 2048 : (mc_ll > 65536 ? 65536 : mc_ll));

    unsigned short* xcat_c = (unsigned short*)alloc((size_t)Mc * 256 * 2);
    unsigned short* h0_c   = (unsigned short*)alloc((size_t)Mc * H * 2);  // also h2
    unsigned short* h1_c   = (unsigned short*)alloc((size_t)Mc * H * 2);

    hipMemsetAsync(pool, 0, (size_t)B * H * 4, stream);

    // ---- weights: convert once ----
    pack_cat_k<<<(H * 32) / 256, 256, 0, stream>>>(W_seed, W_node, wcat, H * 32);
    cvt_k<<<(H * H / 8) / 256, 256, 0, stream>>>(W1, W1b, H * H / 8);
    cvt_k<<<(H * H / 8) / 256, 256, 0, stream>>>(W2, W2b, H * H / 8);

    // ---- chunked row pipeline ----
    for (int base = 0; base < N; base += Mc) {
        const int m = (N - base < Mc) ? (N - base) : Mc;   // multiple of 2048
        pack_cat_k<<<(m * 32) / 256, 256, 0, stream>>>(
            x_seeds + (size_t)base * 128, x_nodes + (size_t)base * 128, xcat_c, m * 32);
        const int grid = (m / 128) * (H / 128);
        gemm_bt_k<0><<<grid, 256, 0, stream>>>(xcat_c, wcat, nullptr, h0_c, m, H, 256);
        gemm_bt_k<1><<<grid, 256, 0, stream>>>(h0_c, W1b, b1, h1_c, m, H, H);
        gemm_bt_k<1><<<grid, 256, 0, stream>>>(h1_c, W2b, b2, h0_c, m, H, H);  // h2 -> h0_c
        scores_k<<<m / 4, 256, 0, stream>>>(h0_c, w_ns, scores + base);
        pool_k<<<(m / 2048) * 32, 256, 0, stream>>>(h0_c, pool + (size_t)(base / 2048) * H);
    }

    stop_k<<<B, 256, 0, stream>>>(pool, W_stop, stp, out);
    node_k<<<B, 256, 0, stream>>>(scores, stp, out);
}

// Round 8
// 1012.979 us; speedup vs baseline: 1.2310x; 1.2310x over previous
//
#include <hip/hip_runtime.h>

typedef float f32x4 __attribute__((ext_vector_type(4)));
typedef __bf16 bf16x8 __attribute__((ext_vector_type(8)));
typedef unsigned short u16x8 __attribute__((ext_vector_type(8)));

#define DEVINL static __device__ __forceinline__

DEVINL unsigned short f2bf(float f) {
    unsigned int u = __builtin_bit_cast(unsigned int, f);
    u += 0x7fffu + ((u >> 16) & 1u);   // RNE
    return (unsigned short)(u >> 16);
}
DEVINL float bf2f(unsigned short u) {
    unsigned int x = ((unsigned int)u) << 16;
    return __builtin_bit_cast(float, x);
}

// async global->LDS, 16B per lane. LDS dest is wave-uniform base + lane*16.
#define GLD16(gp, lp)                                                          \
    __builtin_amdgcn_global_load_lds(                                          \
        (const __attribute__((address_space(1))) void*)(gp),                   \
        (__attribute__((address_space(3))) void*)(lp), 16, 0, 0)

// ---------------- packing kernels ----------------
__global__ void pack_cat_k(const float* __restrict__ s0, const float* __restrict__ s1,
                           unsigned short* __restrict__ dst, int nchunks) {
    int e = blockIdx.x * 256 + threadIdx.x;   // one 8-elem chunk
    if (e >= nchunks) return;
    int row = e >> 5, ch = e & 31;
    const float* src = (ch < 16) ? (s0 + (size_t)row * 128 + ch * 8)
                                 : (s1 + (size_t)row * 128 + (ch - 16) * 8);
    float4 a = *(const float4*)src;
    float4 b = *(const float4*)(src + 4);
    u16x8 o;
    o[0] = f2bf(a.x); o[1] = f2bf(a.y); o[2] = f2bf(a.z); o[3] = f2bf(a.w);
    o[4] = f2bf(b.x); o[5] = f2bf(b.y); o[6] = f2bf(b.z); o[7] = f2bf(b.w);
    *(u16x8*)(dst + (size_t)e * 8) = o;
}

__global__ void cvt_k(const float* __restrict__ s, unsigned short* __restrict__ d, int nchunks) {
    int e = blockIdx.x * 256 + threadIdx.x;
    if (e >= nchunks) return;
    float4 a = *(const float4*)(s + (size_t)e * 8);
    float4 b = *(const float4*)(s + (size_t)e * 8 + 4);
    u16x8 o;
    o[0] = f2bf(a.x); o[1] = f2bf(a.y); o[2] = f2bf(a.z); o[3] = f2bf(a.w);
    o[4] = f2bf(b.x); o[5] = f2bf(b.y); o[6] = f2bf(b.z); o[7] = f2bf(b.w);
    *(u16x8*)(d + (size_t)e * 8) = o;
}

// ---------------- GEMM: A @ B^T with fused epilogues ----------------
// A: [M,K] bf16 row-major, B: [N,K] bf16 row-major.
// 128x128 tile, BK=32, 4 waves (2x2), each wave 64x64 via 4x4 16x16x32 MFMA.
// EPI 0: C = A@B^T (bf16 store)
// EPI 1: C = swish(A@B^T + bias) (bf16 store)
// EPI 2: h = swish(A@B^T + bias); NO store; atomically accumulate
//        sc[row] += h[row,:].wns and pl[seg,col] += mean contribution.
// XCD-aware bijective blockIdx swizzle (T1): 8 consecutive logical tiles
// (sharing an A-panel) land on the same XCD's L2.
template <int EPI>
__global__ void gemm_bt_k(const unsigned short* __restrict__ A,
                          const unsigned short* __restrict__ B,
                          const float* __restrict__ bias,
                          unsigned short* __restrict__ C,
                          const float* __restrict__ wns,
                          float* __restrict__ sc,
                          float* __restrict__ pl,
                          int M, int N, int K) {
    __shared__ unsigned short As[128 * 32];
    __shared__ unsigned short Bs[128 * 32];
    const int tid  = threadIdx.x;
    const int lane = tid & 63;
    const int wv   = tid >> 6;
    const int wr   = wv >> 1, wc = wv & 1;
    const int ntn  = N >> 7;

    // T1: bijective XCD swizzle (hardware round-robins orig%8 across XCDs)
    const int nwg = gridDim.x;
    const int xcd = blockIdx.x & 7, blk = blockIdx.x >> 3;
    const int q = nwg >> 3, rr = nwg & 7;
    const int logical = (xcd < rr ? xcd * (q + 1) : rr * (q + 1) + (xcd - rr) * q) + blk;

    const int im   = logical / ntn, in = logical % ntn;
    const size_t rowA0 = (size_t)im * 128, rowB0 = (size_t)in * 128;

    const int e0 = tid, e1 = tid + 256;
    const int ra0 = e0 >> 2, ca0 = (e0 & 3) * 8;
    const int ra1 = e1 >> 2, ca1 = (e1 & 3) * 8;

    f32x4 acc[4][4] = {};

    const int frow = lane & 15;          // fragment row within 16
    const int kb   = (lane >> 4) * 8;    // k-chunk base

    for (int k0 = 0; k0 < K; k0 += 32) {
        GLD16(A + (rowA0 + ra0) * K + k0 + ca0, (char*)As + e0 * 16);
        GLD16(A + (rowA0 + ra1) * K + k0 + ca1, (char*)As + e1 * 16);
        GLD16(B + (rowB0 + ra0) * K + k0 + ca0, (char*)Bs + e0 * 16);
        GLD16(B + (rowB0 + ra1) * K + k0 + ca1, (char*)Bs + e1 * 16);
        __syncthreads();

        bf16x8 af[4], bfr[4];
#pragma unroll
        for (int m = 0; m < 4; ++m)
            af[m] = *(const bf16x8*)&As[(wr * 64 + m * 16 + frow) * 32 + kb];
#pragma unroll
        for (int n = 0; n < 4; ++n)
            bfr[n] = *(const bf16x8*)&Bs[(wc * 64 + n * 16 + frow) * 32 + kb];
#pragma unroll
        for (int m = 0; m < 4; ++m)
#pragma unroll
            for (int n = 0; n < 4; ++n)
                acc[m][n] = __builtin_amdgcn_mfma_f32_16x16x32_bf16(af[m], bfr[n], acc[m][n], 0, 0, 0);
        __syncthreads();
    }

    // C/D layout: col = lane&15, row = (lane>>4)*4 + reg
    const int r4 = (lane >> 4) * 4;
    const int cc = lane & 15;

    if (EPI == 2) {
        // swish in place
#pragma unroll
        for (int n = 0; n < 4; ++n) {
            const float bv = bias[(int)rowB0 + wc * 64 + n * 16 + cc];
#pragma unroll
            for (int m = 0; m < 4; ++m)
#pragma unroll
                for (int r = 0; r < 4; ++r) {
                    float v = acc[m][n][r] + bv;
                    acc[m][n][r] = v / (1.0f + __expf(-v));
                }
        }
        // node scores: per-(m,r) row partial over this wave's 64 cols
#pragma unroll
        for (int m = 0; m < 4; ++m)
#pragma unroll
            for (int r = 0; r < 4; ++r) {
                float s = 0.f;
#pragma unroll
                for (int n = 0; n < 4; ++n)
                    s += acc[m][n][r] * wns[(int)rowB0 + wc * 64 + n * 16 + cc];
#pragma unroll
                for (int o = 1; o < 16; o <<= 1) s += __shfl_xor(s, o);
                if (cc == 0)
                    atomicAdd(&sc[rowA0 + wr * 64 + m * 16 + r4 + r], s);
            }
        // pool: per-n column partial over this wave's 64 rows
        const int seg = (int)(rowA0 >> 11);
#pragma unroll
        for (int n = 0; n < 4; ++n) {
            float p = 0.f;
#pragma unroll
            for (int m = 0; m < 4; ++m)
#pragma unroll
                for (int r = 0; r < 4; ++r) p += acc[m][n][r];
            p += __shfl_xor(p, 16);
            p += __shfl_xor(p, 32);
            if ((lane >> 4) == 0)
                atomicAdd(&pl[seg * 1024 + (int)rowB0 + wc * 64 + n * 16 + cc],
                          p * (1.0f / 2048.0f));
        }
        return;
    }

#pragma unroll
    for (int n = 0; n < 4; ++n) {
        const int col = (int)rowB0 + wc * 64 + n * 16 + cc;
        const float bv = (EPI == 1) ? bias[col] : 0.0f;
#pragma unroll
        for (int m = 0; m < 4; ++m) {
            const size_t row = rowA0 + wr * 64 + m * 16 + r4;
#pragma unroll
            for (int r = 0; r < 4; ++r) {
                float v = acc[m][n][r] + bv;
                if (EPI == 1) v = v / (1.0f + __expf(-v));   // swish
                C[(row + r) * (size_t)N + col] = f2bf(v);
            }
        }
    }
}

// ---------------- stop head: log_softmax(pool @ W_stop^T) ----------------
__global__ void stop_k(const float* __restrict__ pool, const float* __restrict__ Wstop,
                       float* __restrict__ stp, float* __restrict__ out) {
    const int b = blockIdx.x, t = threadIdx.x;
    float a0 = 0.f, a1 = 0.f;
#pragma unroll
    for (int j = 0; j < 4; ++j) {
        const int hcol = t + j * 256;
        const float pv = pool[b * 1024 + hcol];
        a0 += pv * Wstop[hcol];
        a1 += pv * Wstop[1024 + hcol];
    }
    const int lane = t & 63, wv = t >> 6;
#pragma unroll
    for (int off = 32; off; off >>= 1) { a0 += __shfl_down(a0, off); a1 += __shfl_down(a1, off); }
    __shared__ float r0[4], r1[4];
    if (lane == 0) { r0[wv] = a0; r1[wv] = a1; }
    __syncthreads();
    if (t == 0) {
        const float s0 = r0[0] + r0[1] + r0[2] + r0[3];
        const float s1 = r1[0] + r1[1] + r1[2] + r1[3];
        const float m  = fmaxf(s0, s1);
        const float lse = m + __logf(__expf(s0 - m) + __expf(s1 - m));
        stp[b * 2] = s0 - lse;
        out[(size_t)b * 2049 + 2048] = s1 - lse;
    }
}

// ---------------- node logits: log_softmax over 2048 + stop0 ----------------
__global__ void node_k(const float* __restrict__ sc, const float* __restrict__ stp,
                       float* __restrict__ out) {
    const int b = blockIdx.x, t = threadIdx.x;
    const float* s = sc + (size_t)b * 2048;
    float v[8];
    float mx = -3.4e38f;
#pragma unroll
    for (int j = 0; j < 8; ++j) { v[j] = s[t + j * 256]; mx = fmaxf(mx, v[j]); }
    const int lane = t & 63, wv = t >> 6;
    __shared__ float red[4];
#pragma unroll
    for (int off = 32; off; off >>= 1) mx = fmaxf(mx, __shfl_down(mx, off));
    if (lane == 0) red[wv] = mx;
    __syncthreads();
    mx = fmaxf(fmaxf(red[0], red[1]), fmaxf(red[2], red[3]));
    float se = 0.f;
#pragma unroll
    for (int j = 0; j < 8; ++j) se += __expf(v[j] - mx);
    __syncthreads();
#pragma unroll
    for (int off = 32; off; off >>= 1) se += __shfl_down(se, off);
    if (lane == 0) red[wv] = se;
    __syncthreads();
    se = red[0] + red[1] + red[2] + red[3];
    const float base = stp[b * 2] - mx - __logf(se);
#pragma unroll
    for (int j = 0; j < 8; ++j) out[(size_t)b * 2049 + t + j * 256] = v[j] + base;
}

extern "C" void kernel_launch(void* const* d_in, const int* in_sizes, int n_in,
                              void* d_out, int out_size, void* d_ws, size_t ws_size,
                              hipStream_t stream) {
    (void)in_sizes; (void)n_in; (void)out_size;
    const float* x_seeds = (const float*)d_in[0];
    const float* x_nodes = (const float*)d_in[1];
    const float* W_seed  = (const float*)d_in[2];
    const float* W_node  = (const float*)d_in[3];
    const float* W1      = (const float*)d_in[4];
    const float* b1      = (const float*)d_in[5];
    const float* W2      = (const float*)d_in[6];
    const float* b2      = (const float*)d_in[7];
    const float* w_ns    = (const float*)d_in[8];
    const float* W_stop  = (const float*)d_in[9];
    float* out = (float*)d_out;

    const int N = 131072, H = 1024, B = 64;

    char* ws = (char*)d_ws;
    size_t off = 0;
    auto alloc = [&](size_t bytes) {
        char* p = ws + off;
        off += (bytes + 255) & ~(size_t)255;
        return p;
    };
    // ---- persistent (small) buffers ----
    unsigned short* wcat = (unsigned short*)alloc((size_t)H * 256 * 2);   // 0.5 MB
    unsigned short* W1b  = (unsigned short*)alloc((size_t)H * H * 2);     // 2 MB
    unsigned short* W2b  = (unsigned short*)alloc((size_t)H * H * 2);     // 2 MB
    float* scores = (float*)alloc((size_t)N * 4);                         // 0.5 MB
    float* pool   = (float*)alloc((size_t)B * H * 4);                     // 0.25 MB
    float* stp    = (float*)alloc((size_t)B * 2 * 4);

    // ---- chunk sizing (per-row: 512B xcat + 2048B h0 + 2048B h1) ----
    const size_t per_row = 256 * 2 + 1024 * 2 + 1024 * 2;   // 4608 B
    size_t avail = (ws_size > off + (1u << 20)) ? (ws_size - off - (1u << 20)) : 0;
    long long mc_ll = (long long)(avail / per_row) / 2048 * 2048;
    int Mc = (int)(mc_ll < 2048 ? 2048 : (mc_ll > 65536 ? 65536 : mc_ll));

    unsigned short* xcat_c = (unsigned short*)alloc((size_t)Mc * 256 * 2);
    unsigned short* h0_c   = (unsigned short*)alloc((size_t)Mc * H * 2);
    unsigned short* h1_c   = (unsigned short*)alloc((size_t)Mc * H * 2);

    hipMemsetAsync(pool, 0, (size_t)B * H * 4, stream);
    hipMemsetAsync(scores, 0, (size_t)N * 4, stream);   // accumulated via atomics

    // ---- weights: convert once ----
    pack_cat_k<<<(H * 32) / 256, 256, 0, stream>>>(W_seed, W_node, wcat, H * 32);
    cvt_k<<<(H * H / 8) / 256, 256, 0, stream>>>(W1, W1b, H * H / 8);
    cvt_k<<<(H * H / 8) / 256, 256, 0, stream>>>(W2, W2b, H * H / 8);

    // ---- chunked row pipeline ----
    for (int base = 0; base < N; base += Mc) {
        const int m = (N - base < Mc) ? (N - base) : Mc;   // multiple of 2048
        pack_cat_k<<<(m * 32) / 256, 256, 0, stream>>>(
            x_seeds + (size_t)base * 128, x_nodes + (size_t)base * 128, xcat_c, m * 32);
        const int grid = (m / 128) * (H / 128);
        gemm_bt_k<0><<<grid, 256, 0, stream>>>(xcat_c, wcat, nullptr, h0_c,
                                               nullptr, nullptr, nullptr, m, H, 256);
        gemm_bt_k<1><<<grid, 256, 0, stream>>>(h0_c, W1b, b1, h1_c,
                                               nullptr, nullptr, nullptr, m, H, H);
        gemm_bt_k<2><<<grid, 256, 0, stream>>>(h1_c, W2b, b2, nullptr,
                                               w_ns, scores + base,
                                               pool + (size_t)(base / 2048) * H, m, H, H);
    }

    stop_k<<<B, 256, 0, stream>>>(pool, W_stop, stp, out);
    node_k<<<B, 256, 0, stream>>>(scores, stp, out);
}